// Round 1
// baseline (490.651 us; speedup 1.0000x reference)
//
#include <hip/hip_runtime.h>
#include <hip/hip_fp16.h>

// Shapes: x (N=8, C=64, D=32, H=64, W=64) fp32, weight (64,), bias (64,)
#define NCH        64
#define DHW        131072           // 32*64*64, contiguous per (n,c) slab
#define NSLAB      512              // N * C
#define ELEMS_PER_CH 1048576        // 8 * DHW

// fake_quant(v) with EXP_BITS=5 / SIG_BITS=10 == RNE fp16 round-trip
// (emax=15, emin=-14 incl. subnormals, maxval=65504; inputs |v| << 65504
//  so the clip-vs-inf difference never triggers).
__device__ __forceinline__ float fq(float v) {
    return __half2float(__float2half_rn(v));
}

// ---------------- Pass 1: per-channel sum & sumsq of fq(x) ----------------
// 1024 blocks x 256 threads; block b handles half of slab b>>1.
// Slab s: n = s/64, c = s%64, base = s*DHW. Each block: 16384 float4.
__global__ __launch_bounds__(256)
void bn_pass1(const float* __restrict__ x, float* __restrict__ sums) {
    const int b    = blockIdx.x;
    const int slab = b >> 1;
    const int half = b & 1;
    const int c    = slab & 63;
    const float4* p = reinterpret_cast<const float4*>(x + (size_t)slab * DHW)
                      + half * 16384;
    float s = 0.f, ss = 0.f;
    #pragma unroll 4
    for (int i = threadIdx.x; i < 16384; i += 256) {
        float4 v = p[i];
        float a0 = fq(v.x), a1 = fq(v.y), a2 = fq(v.z), a3 = fq(v.w);
        s  += (a0 + a1) + (a2 + a3);
        ss += (a0*a0 + a1*a1) + (a2*a2 + a3*a3);
    }
    // wave-64 butterfly reduce
    #pragma unroll
    for (int off = 32; off; off >>= 1) {
        s  += __shfl_down(s, off);
        ss += __shfl_down(ss, off);
    }
    __shared__ float ls[4], lss[4];
    const int wid = threadIdx.x >> 6;
    if ((threadIdx.x & 63) == 0) { ls[wid] = s; lss[wid] = ss; }
    __syncthreads();
    if (threadIdx.x == 0) {
        s  = (ls[0]  + ls[1])  + (ls[2]  + ls[3]);
        ss = (lss[0] + lss[1]) + (lss[2] + lss[3]);
        atomicAdd(&sums[c], s);          // 16 atomics per channel total
        atomicAdd(&sums[NCH + c], ss);
    }
}

// ---------------- Pass 2: per-channel params (1 block, 64 threads) --------
__global__ void bn_pass2(const float* __restrict__ sums,
                         const float* __restrict__ weight,
                         const float* __restrict__ bias,
                         float* __restrict__ params) {
    const int c = threadIdx.x;
    if (c < NCH) {
        const float inv_n = 1.0f / (float)ELEMS_PER_CH;
        float mean = sums[c] * inv_n;
        float var  = sums[NCH + c] * inv_n - mean * mean;  // == E[(x-m)^2] exactly in real arith
        float mq = fq(mean);
        float vq = fq(var);
        float inv_std = 1.0f / sqrtf(vq + 1e-5f);
        float wq = fq(weight[c]);
        float bq = fq(bias[c]);
        params[c]         = mq;
        params[NCH + c]   = inv_std * wq;   // combined scale
        params[2*NCH + c] = bq;
    }
}

// ---------------- Pass 3: elementwise normalize + requant -----------------
// 2048 blocks x 256 threads; block b handles quarter (b&3) of slab b>>2.
__global__ __launch_bounds__(256)
void bn_pass3(const float* __restrict__ x, float* __restrict__ out,
              const float* __restrict__ params) {
    const int b     = blockIdx.x;
    const int slab  = b >> 2;
    const int quart = b & 3;
    const int c     = slab & 63;
    const float mq = params[c];
    const float sc = params[NCH + c];
    const float bq = params[2*NCH + c];
    const size_t base = (size_t)slab * DHW;
    const float4* p = reinterpret_cast<const float4*>(x + base)   + quart * 8192;
    float4*       q = reinterpret_cast<float4*>(out + base)       + quart * 8192;
    #pragma unroll 4
    for (int i = threadIdx.x; i < 8192; i += 256) {
        float4 v = p[i];
        float4 r;
        r.x = fq((fq(v.x) - mq) * sc + bq);
        r.y = fq((fq(v.y) - mq) * sc + bq);
        r.z = fq((fq(v.z) - mq) * sc + bq);
        r.w = fq((fq(v.w) - mq) * sc + bq);
        q[i] = r;
    }
}

extern "C" void kernel_launch(void* const* d_in, const int* in_sizes, int n_in,
                              void* d_out, int out_size, void* d_ws, size_t ws_size,
                              hipStream_t stream) {
    const float* x      = (const float*)d_in[0];
    const float* weight = (const float*)d_in[1];
    const float* bias   = (const float*)d_in[2];
    float* out   = (float*)d_out;
    float* sums  = (float*)d_ws;        // [2*NCH] fp32 accumulators
    float* params = sums + 2 * NCH;     // [3*NCH] fp32 params

    // ws is poisoned 0xAA before every timed launch — zero the accumulators.
    hipMemsetAsync(d_ws, 0, 2 * NCH * sizeof(float), stream);

    bn_pass1<<<1024, 256, 0, stream>>>(x, sums);
    bn_pass2<<<1, 64, 0, stream>>>(sums, weight, bias, params);
    bn_pass3<<<2048, 256, 0, stream>>>(x, out, params);
}

// Round 2
// 478.079 us; speedup vs baseline: 1.0263x; 1.0263x over previous
//
#include <hip/hip_runtime.h>
#include <hip/hip_fp16.h>

// Shapes: x (N=8, C=64, D=32, H=64, W=64) fp32, weight (64,), bias (64,)
#define NCH         64
#define DHW         131072        // 32*64*64 contiguous elems per (n,c) slab
#define QUARTER_F4  8192          // float4 per quarter-slab (DHW/4/4)
#define NBLK        2048          // 512 slabs * 4 quarters; == 8 blocks/CU exactly
#define ELEMS_PER_CH 1048576.0f   // 8 * DHW

typedef float f4 __attribute__((ext_vector_type(4)));

// fake_quant(v) with EXP_BITS=5 / SIG_BITS=10 == RNE fp16 round-trip
// (emax=15, emin=-14 incl. subnormals, maxval=65504; |inputs| << 65504 so
//  the clip-vs-inf difference never triggers). Verified: absmax 0.031.
__device__ __forceinline__ float fq(float v) {
    return __half2float(__float2half_rn(v));
}

// ---------- Pass 1: per-block partial sum / sumsq of fq(x) ----------------
// Block b owns quarter (b&3) of slab (b>>2); writes part[b], part[NBLK+b].
// No atomics, no zero-init needed (every slot written exactly once).
__global__ __launch_bounds__(256)
void bn_stats(const float* __restrict__ x, float* __restrict__ part) {
    const int b = blockIdx.x;
    const f4* p = reinterpret_cast<const f4*>(x) + (size_t)b * QUARTER_F4;
    float s0 = 0.f, s1 = 0.f, ss0 = 0.f, ss1 = 0.f;
    #pragma unroll 8
    for (int i = threadIdx.x; i < QUARTER_F4; i += 256) {
        f4 v = p[i];
        float a0 = fq(v.x), a1 = fq(v.y), a2 = fq(v.z), a3 = fq(v.w);
        s0 += a0 + a1;
        s1 += a2 + a3;
        ss0 = fmaf(a0, a0, ss0); ss0 = fmaf(a1, a1, ss0);
        ss1 = fmaf(a2, a2, ss1); ss1 = fmaf(a3, a3, ss1);
    }
    float s = s0 + s1, ss = ss0 + ss1;
    #pragma unroll
    for (int off = 32; off; off >>= 1) {
        s  += __shfl_down(s, off);
        ss += __shfl_down(ss, off);
    }
    __shared__ float ls[4], lss[4];
    const int wid = threadIdx.x >> 6;
    if ((threadIdx.x & 63) == 0) { ls[wid] = s; lss[wid] = ss; }
    __syncthreads();
    if (threadIdx.x == 0) {
        part[b]        = (ls[0]  + ls[1])  + (ls[2]  + ls[3]);
        part[NBLK + b] = (lss[0] + lss[1]) + (lss[2] + lss[3]);
    }
}

// ---------- Pass 2: reduce partials -> per-channel params (1 block) -------
// Channel c's blocks: b = 256*n + 4*c + q, n in [0,8), q in [0,4).
__global__ void bn_params(const float* __restrict__ part,
                          const float* __restrict__ weight,
                          const float* __restrict__ bias,
                          float* __restrict__ params) {
    const int c = threadIdx.x;  // 64 threads
    float s = 0.f, ss = 0.f;
    #pragma unroll
    for (int n = 0; n < 8; ++n)
        #pragma unroll
        for (int q = 0; q < 4; ++q) {
            const int b = 256 * n + 4 * c + q;
            s  += part[b];
            ss += part[NBLK + b];
        }
    const float inv_n = 1.0f / ELEMS_PER_CH;
    float mean = s * inv_n;
    float var  = ss * inv_n - mean * mean;   // == E[(x-m)^2] in exact arith
    float mq = fq(mean);
    float vq = fq(var);
    float inv_std = 1.0f / sqrtf(vq + 1e-5f);
    params[c]           = mq;
    params[NCH + c]     = inv_std * fq(weight[c]);  // combined scale
    params[2 * NCH + c] = fq(bias[c]);
}

// ---------- Pass 3: elementwise normalize + requant -----------------------
// x (256 MiB) should be L3-resident after pass 1; nontemporal stores keep
// the 256 MB of output writes from evicting x ahead of the read cursor.
__global__ __launch_bounds__(256)
void bn_apply(const float* __restrict__ x, float* __restrict__ out,
              const float* __restrict__ params) {
    const int b = blockIdx.x;
    const int c = (b >> 2) & 63;
    const float mq = params[c];
    const float sc = params[NCH + c];
    const float bq = params[2 * NCH + c];
    const f4* p = reinterpret_cast<const f4*>(x)  + (size_t)b * QUARTER_F4;
    f4*       q = reinterpret_cast<f4*>(out)      + (size_t)b * QUARTER_F4;
    #pragma unroll 8
    for (int i = threadIdx.x; i < QUARTER_F4; i += 256) {
        f4 v = p[i];
        f4 r;
        r.x = fq(fmaf(fq(v.x) - mq, sc, bq));
        r.y = fq(fmaf(fq(v.y) - mq, sc, bq));
        r.z = fq(fmaf(fq(v.z) - mq, sc, bq));
        r.w = fq(fmaf(fq(v.w) - mq, sc, bq));
        __builtin_nontemporal_store(r, q + i);
    }
}

extern "C" void kernel_launch(void* const* d_in, const int* in_sizes, int n_in,
                              void* d_out, int out_size, void* d_ws, size_t ws_size,
                              hipStream_t stream) {
    const float* x      = (const float*)d_in[0];
    const float* weight = (const float*)d_in[1];
    const float* bias   = (const float*)d_in[2];
    float* out    = (float*)d_out;
    float* part   = (float*)d_ws;          // [2*NBLK] fp32 partials (all written)
    float* params = part + 2 * NBLK;       // [3*NCH]  fp32 params

    bn_stats <<<NBLK, 256, 0, stream>>>(x, part);
    bn_params<<<1,    64,  0, stream>>>(part, weight, bias, params);
    bn_apply <<<NBLK, 256, 0, stream>>>(x, out, params);
}

// Round 3
// 474.623 us; speedup vs baseline: 1.0338x; 1.0073x over previous
//
#include <hip/hip_runtime.h>
#include <hip/hip_fp16.h>

// Shapes: x (N=8, C=64, D=32, H=64, W=64) fp32, weight (64,), bias (64,)
#define NCH         64
#define DHW         131072        // 32*64*64 contiguous elems per (n,c) slab
#define QUARTER_F4  8192          // float4 per quarter-slab (DHW/4/4)
#define NBLK        2048          // 512 slabs * 4 quarters; == 8 blocks/CU exactly
#define ELEMS_PER_CH 1048576.0f   // 8 * DHW

typedef float f4 __attribute__((ext_vector_type(4)));

// fake_quant(v) with EXP_BITS=5 / SIG_BITS=10 == RNE fp16 round-trip
// (emax=15, emin=-14 incl. subnormals, maxval=65504; |inputs| << 65504 so
//  the clip-vs-inf difference never triggers). Verified: absmax 0.031.
__device__ __forceinline__ float fq(float v) {
    return __half2float(__float2half_rn(v));
}

// ---------- Pass 1: per-block partial sum / sumsq of fq(x) ----------------
// Block b owns quarter (b&3) of slab (b>>2); writes part[b], part[NBLK+b].
// Normal (caching) loads: this pass populates L3 with x for pass 3.
__global__ __launch_bounds__(256)
void bn_stats(const float* __restrict__ x, float* __restrict__ part) {
    const int b = blockIdx.x;
    const f4* p = reinterpret_cast<const f4*>(x) + (size_t)b * QUARTER_F4;
    float s0 = 0.f, s1 = 0.f, ss0 = 0.f, ss1 = 0.f;
    #pragma unroll 8
    for (int i = threadIdx.x; i < QUARTER_F4; i += 256) {
        f4 v = p[i];
        float a0 = fq(v.x), a1 = fq(v.y), a2 = fq(v.z), a3 = fq(v.w);
        s0 += a0 + a1;
        s1 += a2 + a3;
        ss0 = fmaf(a0, a0, ss0); ss0 = fmaf(a1, a1, ss0);
        ss1 = fmaf(a2, a2, ss1); ss1 = fmaf(a3, a3, ss1);
    }
    float s = s0 + s1, ss = ss0 + ss1;
    #pragma unroll
    for (int off = 32; off; off >>= 1) {
        s  += __shfl_down(s, off);
        ss += __shfl_down(ss, off);
    }
    __shared__ float ls[4], lss[4];
    const int wid = threadIdx.x >> 6;
    if ((threadIdx.x & 63) == 0) { ls[wid] = s; lss[wid] = ss; }
    __syncthreads();
    if (threadIdx.x == 0) {
        part[b]        = (ls[0]  + ls[1])  + (ls[2]  + ls[3]);
        part[NBLK + b] = (lss[0] + lss[1]) + (lss[2] + lss[3]);
    }
}

// ---------- Pass 2: reduce partials -> per-channel params (1 block) -------
// Channel c's blocks: b = 256*n + 4*c + q, n in [0,8), q in [0,4).
__global__ void bn_params(const float* __restrict__ part,
                          const float* __restrict__ weight,
                          const float* __restrict__ bias,
                          float* __restrict__ params) {
    const int c = threadIdx.x;  // 64 threads
    float s = 0.f, ss = 0.f;
    #pragma unroll
    for (int n = 0; n < 8; ++n)
        #pragma unroll
        for (int q = 0; q < 4; ++q) {
            const int b = 256 * n + 4 * c + q;
            s  += part[b];
            ss += part[NBLK + b];
        }
    const float inv_n = 1.0f / ELEMS_PER_CH;
    float mean = s * inv_n;
    float var  = ss * inv_n - mean * mean;   // == E[(x-m)^2] in exact arith
    float mq = fq(mean);
    float vq = fq(var);
    float inv_std = 1.0f / sqrtf(vq + 1e-5f);
    params[c]           = mq;
    params[NCH + c]     = inv_std * fq(weight[c]);  // combined scale
    params[2 * NCH + c] = fq(bias[c]);
}

// ---------- Pass 3: elementwise normalize + requant -----------------------
// Both grids are fully co-resident (8 blocks/CU), so after pass 1 the L3
// holds ~the TAIL (high-i lines) of each block's 512 KiB region. Consume
// that tail first (reverse inner iteration); nontemporal loads keep misses
// from evicting other regions' unconsumed tails; nontemporal stores keep
// the 256 MB output stream out of L3 entirely.
__global__ __launch_bounds__(256)
void bn_apply(const float* __restrict__ x, float* __restrict__ out,
              const float* __restrict__ params) {
    const int b = blockIdx.x;
    const int c = (b >> 2) & 63;
    const float mq = params[c];
    const float sc = params[NCH + c];
    const float bq = params[2 * NCH + c];
    const f4* p = reinterpret_cast<const f4*>(x)  + (size_t)b * QUARTER_F4;
    f4*       q = reinterpret_cast<f4*>(out)      + (size_t)b * QUARTER_F4;
    // reverse traversal: i = QUARTER_F4-256+tid, QUARTER_F4-512+tid, ... tid
    #pragma unroll 8
    for (int i = (int)(QUARTER_F4 - 256) + (int)threadIdx.x; i >= 0; i -= 256) {
        f4 v = __builtin_nontemporal_load(p + i);
        f4 r;
        r.x = fq(fmaf(fq(v.x) - mq, sc, bq));
        r.y = fq(fmaf(fq(v.y) - mq, sc, bq));
        r.z = fq(fmaf(fq(v.z) - mq, sc, bq));
        r.w = fq(fmaf(fq(v.w) - mq, sc, bq));
        __builtin_nontemporal_store(r, q + i);
    }
}

extern "C" void kernel_launch(void* const* d_in, const int* in_sizes, int n_in,
                              void* d_out, int out_size, void* d_ws, size_t ws_size,
                              hipStream_t stream) {
    const float* x      = (const float*)d_in[0];
    const float* weight = (const float*)d_in[1];
    const float* bias   = (const float*)d_in[2];
    float* out    = (float*)d_out;
    float* part   = (float*)d_ws;          // [2*NBLK] fp32 partials (all written)
    float* params = part + 2 * NBLK;       // [3*NCH]  fp32 params

    bn_stats <<<NBLK, 256, 0, stream>>>(x, part);
    bn_params<<<1,    64,  0, stream>>>(part, weight, bias, params);
    bn_apply <<<NBLK, 256, 0, stream>>>(x, out, params);
}